// Round 5
// baseline (1836.142 us; speedup 1.0000x reference)
//
#include <hip/hip_runtime.h>
#include <math.h>

#define QN 8
#define CN 1024
#define DN 256
#define NROWS 32768
#define RPW 64

#define LOSS_OFF 8388608
#define IDX_OFF  8388609

// ---------------------------------------------------------------------------
// Kernel 1: normalize codebooks, store transposed: cbnt[q][k][c]
// (unchanged from rounds 1-4 — verified correct)
// ---------------------------------------------------------------------------
__global__ void rvq_normalize_cb(const float* __restrict__ cb,
                                 float* __restrict__ cbnt,
                                 float* __restrict__ out) {
    if (blockIdx.x == 0 && threadIdx.x == 0) out[LOSS_OFF] = 0.0f;
    const int wave = threadIdx.x >> 6;
    const int lane = threadIdx.x & 63;
    const int cw = blockIdx.x * 4 + wave;          // 0..8191
    const int q = cw >> 10;
    const int c = cw & (CN - 1);
    float4 v = reinterpret_cast<const float4*>(cb + (size_t)cw * DN)[lane];
    float ss = v.x * v.x + v.y * v.y + v.z * v.z + v.w * v.w;
#pragma unroll
    for (int m = 1; m < 64; m <<= 1) ss += __shfl_xor(ss, m, 64);
    const float inv = 1.0f / fmaxf(sqrtf(ss), 1e-12f);
    float* dst = cbnt + (size_t)q * (DN * CN) + (size_t)(lane * 4) * CN + c;
    dst[0 * CN] = v.x * inv;
    dst[1 * CN] = v.y * inv;
    dst[2 * CN] = v.z * inv;
    dst[3 * CN] = v.w * inv;
}

// async global->LDS, 16B per lane (dest = wave-uniform base + lane*16)
__device__ __forceinline__ void acp16(float* lds_dst, const float* gsrc) {
    __builtin_amdgcn_global_load_lds(
        (const __attribute__((address_space(1))) unsigned int*)gsrc,
        (__attribute__((address_space(3))) unsigned int*)lds_dst, 16, 0, 0);
}

// 8 rows x 8 cods per thread, all accumulators individually named.
// Thread's cods within the 512-chunk: {cg*4+e} (aA) and {256+cg*4+e} (aB).
#define DECL_ROW(j) float4 aA##j = make_float4(0.f,0.f,0.f,0.f), \
                           aB##j = make_float4(0.f,0.f,0.f,0.f);

#define FMA_ROW(j, S) \
    aA##j.x = fmaf(S, b0.x, aA##j.x); aA##j.y = fmaf(S, b0.y, aA##j.y); \
    aA##j.z = fmaf(S, b0.z, aA##j.z); aA##j.w = fmaf(S, b0.w, aA##j.w); \
    aB##j.x = fmaf(S, b1.x, aB##j.x); aB##j.y = fmaf(S, b1.y, aB##j.y); \
    aB##j.z = fmaf(S, b1.z, aB##j.z); aB##j.w = fmaf(S, b1.w, aB##j.w);

#define KKSTEP(kk) { \
    const float4 a0 = *reinterpret_cast<const float4*>(&At[kt4 + (kk)][w8]); \
    const float4 a1 = *reinterpret_cast<const float4*>(&At[kt4 + (kk)][w8 + 4]); \
    const float4 b0 = *reinterpret_cast<const float4*>(&Btl[bb][kk][cg4]); \
    const float4 b1 = *reinterpret_cast<const float4*>(&Btl[bb][kk][256 + cg4]); \
    FMA_ROW(0, a0.x) FMA_ROW(1, a0.y) FMA_ROW(2, a0.z) FMA_ROW(3, a0.w) \
    FMA_ROW(4, a1.x) FMA_ROW(5, a1.y) FMA_ROW(6, a1.z) FMA_ROW(7, a1.w) }

// ascending cods within thread (cg*4+0..3 < 256+cg*4+0..3); strict > keeps first
#define FOLDMERGE(j) { \
    float bv = -INFINITY; int bi = 0; \
    const int cA = coff + cg4; \
    if (aA##j.x > bv) { bv = aA##j.x; bi = cA + 0; } \
    if (aA##j.y > bv) { bv = aA##j.y; bi = cA + 1; } \
    if (aA##j.z > bv) { bv = aA##j.z; bi = cA + 2; } \
    if (aA##j.w > bv) { bv = aA##j.w; bi = cA + 3; } \
    if (aB##j.x > bv) { bv = aB##j.x; bi = cA + 256; } \
    if (aB##j.y > bv) { bv = aB##j.y; bi = cA + 257; } \
    if (aB##j.z > bv) { bv = aB##j.z; bi = cA + 258; } \
    if (aB##j.w > bv) { bv = aB##j.w; bi = cA + 259; } \
    _Pragma("unroll") \
    for (int m = 1; m < 64; m <<= 1) { \
        const float ov = __shfl_xor(bv, m, 64); \
        const int   oi = __shfl_xor(bi, m, 64); \
        if (ov > bv || (ov == bv && oi < bi)) { bv = ov; bi = oi; } } \
    if (bv > rv##j) { rv##j = bv; ri##j = bi; } }

// stage one 4k x 512c B-tile (8 KiB): ONE acp16 per thread, linear LDS dest
#define STAGE(nb, tile) { \
    const float* s_ = cbtq + (size_t)(((tile) * 4 + (t >> 7)) * 1024) + coff + ((t & 127) << 2); \
    acp16(Bflat + (nb) * 2048 + (t << 2), s_); }

// ---------------------------------------------------------------------------
// Kernel 2: persistent RVQ, 512-thread WG owns 64 rows through all 8 stages.
// Residual in LDS At[k][row]; B double-buffered 4k x 512c tiles.
// 16 waves/CU (4/SIMD) for latency hiding; VGPR capped at 128.
// fmaf chain per (row,cod) is k=0..255 sequential — bit-identical to rounds 2/4.
// ---------------------------------------------------------------------------
__global__ __launch_bounds__(512, 4)
void rvq_main(const float* __restrict__ in,
              const float* __restrict__ cb,
              const float* __restrict__ cbnt,
              float* __restrict__ out) {
    __shared__ float At[DN][RPW];       // 64 KiB residual, transposed [k][row]
    __shared__ float Btl[2][4][512];    // 16 KiB: dbuf of 4k x 512c tiles
    float* Bflat = &Btl[0][0][0];
    int*   sIdx  = reinterpret_cast<int*>(Bflat);        // alias (64 ints, buf0)
    float* red   = Bflat + 64;                           // alias (8 floats)

    const int t    = threadIdx.x;
    const int r    = t & 63;            // row for elementwise phases
    const int w    = t >> 6;            // wave id 0..7 == GEMM row-group
    const int w8   = w << 3;
    const int cg4  = (t & 63) << 2;     // cod-group base within 512-chunk
    const int base = blockIdx.x * RPW;

    // residual := inputs; wave w handles k in [w*32, w*32+32) for all its lanes' rows
#pragma unroll
    for (int i = 0; i < 8; ++i) {
        const int k0 = (w << 5) + (i << 2);
        const float4 v = *reinterpret_cast<const float4*>(in + (size_t)(base + r) * DN + k0);
        At[k0 + 0][r] = v.x;
        At[k0 + 1][r] = v.y;
        At[k0 + 2][r] = v.z;
        At[k0 + 3][r] = v.w;
    }

    float lossAcc = 0.0f;

    for (int q = 0; q < QN; ++q) {
        const float* cbq  = cb   + (size_t)q * (CN * DN);
        const float* cbtq = cbnt + (size_t)q * (DN * CN);
        float rv0 = -INFINITY, rv1 = -INFINITY, rv2 = -INFINITY, rv3 = -INFINITY,
              rv4 = -INFINITY, rv5 = -INFINITY, rv6 = -INFINITY, rv7 = -INFINITY;
        int ri0 = 0, ri1 = 0, ri2 = 0, ri3 = 0, ri4 = 0, ri5 = 0, ri6 = 0, ri7 = 0;

        __syncthreads();                                 // At ready (init / prev update)

        for (int chunk = 0; chunk < 2; ++chunk) {        // 2 x 512 cods
            const int coff = chunk << 9;
            DECL_ROW(0) DECL_ROW(1) DECL_ROW(2) DECL_ROW(3)
            DECL_ROW(4) DECL_ROW(5) DECL_ROW(6) DECL_ROW(7)

            STAGE(0, 0)                                  // prologue: tile 0 -> buf 0

            for (int tt = 0; tt < 64; ++tt) {            // 64 tiles x 4 k
                __syncthreads();                          // vmcnt drained: buf[tt&1] ready
                const int bb = tt & 1;
                if (tt < 63) STAGE(bb ^ 1, tt + 1)        // next tile; hides under FMAs
                const int kt4 = tt * 4;
                KKSTEP(0) KKSTEP(1) KKSTEP(2) KKSTEP(3)
            }

            FOLDMERGE(0) FOLDMERGE(1) FOLDMERGE(2) FOLDMERGE(3)
            FOLDMERGE(4) FOLDMERGE(5) FOLDMERGE(6) FOLDMERGE(7)
        }

        __syncthreads();                 // everyone done with Btl before alias write
        if ((t & 63) == 0) {
            sIdx[w8 + 0] = ri0; sIdx[w8 + 1] = ri1;
            sIdx[w8 + 2] = ri2; sIdx[w8 + 3] = ri3;
            sIdx[w8 + 4] = ri4; sIdx[w8 + 5] = ri5;
            sIdx[w8 + 6] = ri6; sIdx[w8 + 7] = ri7;
        }
        __syncthreads();
        if (t < 64) out[(size_t)IDX_OFF + (size_t)q * NROWS + base + t] = (float)sIdx[t];

        // residual update + loss: wave w handles k in [w*32, w*32+32), all 64 rows
        {
            const int gi = sIdx[r];
            const float* qrow = cbq + (size_t)gi * DN + (w << 5);
#pragma unroll
            for (int i = 0; i < 8; ++i) {
                const float4 qv = *reinterpret_cast<const float4*>(qrow + (i << 2));
                const int k0 = (w << 5) + (i << 2);
                const float v0 = At[k0 + 0][r] - qv.x;
                const float v1 = At[k0 + 1][r] - qv.y;
                const float v2 = At[k0 + 2][r] - qv.z;
                const float v3 = At[k0 + 3][r] - qv.w;
                At[k0 + 0][r] = v0;
                At[k0 + 1][r] = v1;
                At[k0 + 2][r] = v2;
                At[k0 + 3][r] = v3;
                lossAcc += v0 * v0 + v1 * v1 + v2 * v2 + v3 * v3;
            }
        }
        // next iteration's leading __syncthreads covers At update + sIdx reuse
    }

    __syncthreads();

    // quantized_sum = inputs - residual_final
#pragma unroll
    for (int i = 0; i < 8; ++i) {
        const int k0 = (w << 5) + (i << 2);
        const float4 v = *reinterpret_cast<const float4*>(in + (size_t)(base + r) * DN + k0);
        float4 o;
        o.x = v.x - At[k0 + 0][r];
        o.y = v.y - At[k0 + 1][r];
        o.z = v.z - At[k0 + 2][r];
        o.w = v.w - At[k0 + 3][r];
        *reinterpret_cast<float4*>(out + (size_t)(base + r) * DN + k0) = o;
    }

    // loss: wave butterfly + cross-wave via LDS + one atomic per WG
#pragma unroll
    for (int m = 1; m < 64; m <<= 1) lossAcc += __shfl_xor(lossAcc, m, 64);
    if (r == 0) red[w] = lossAcc;
    __syncthreads();
    if (t == 0) {
        const float tot = red[0] + red[1] + red[2] + red[3]
                        + red[4] + red[5] + red[6] + red[7];
        atomicAdd(out + LOSS_OFF, tot * (1.25f / (8.0f * 8388608.0f)));
    }
}

extern "C" void kernel_launch(void* const* d_in, const int* in_sizes, int n_in,
                              void* d_out, int out_size, void* d_ws, size_t ws_size,
                              hipStream_t stream) {
    (void)in_sizes; (void)n_in; (void)out_size; (void)ws_size;
    const float* in   = (const float*)d_in[0];
    const float* cb   = (const float*)d_in[1];
    float* out        = (float*)d_out;
    float* cbnt       = (float*)d_ws;   // 8 MiB scratch: normalized+transposed codebooks

    rvq_normalize_cb<<<dim3(2048), dim3(256), 0, stream>>>(cb, cbnt, out);
    rvq_main<<<dim3(512), dim3(512), 0, stream>>>(in, cb, cbnt, out);
}

// Round 6
// 1831.628 us; speedup vs baseline: 1.0025x; 1.0025x over previous
//
#include <hip/hip_runtime.h>
#include <math.h>

#define QN 8
#define CN 1024
#define DN 256
#define NROWS 32768
#define RPW 64

#define LOSS_OFF 8388608
#define IDX_OFF  8388609

// ---------------------------------------------------------------------------
// Kernel 1: normalize codebooks, store transposed: cbnt[q][k][c]
// (unchanged from rounds 1-5 — verified correct)
// ---------------------------------------------------------------------------
__global__ void rvq_normalize_cb(const float* __restrict__ cb,
                                 float* __restrict__ cbnt,
                                 float* __restrict__ out) {
    if (blockIdx.x == 0 && threadIdx.x == 0) out[LOSS_OFF] = 0.0f;
    const int wave = threadIdx.x >> 6;
    const int lane = threadIdx.x & 63;
    const int cw = blockIdx.x * 4 + wave;          // 0..8191
    const int q = cw >> 10;
    const int c = cw & (CN - 1);
    float4 v = reinterpret_cast<const float4*>(cb + (size_t)cw * DN)[lane];
    float ss = v.x * v.x + v.y * v.y + v.z * v.z + v.w * v.w;
#pragma unroll
    for (int m = 1; m < 64; m <<= 1) ss += __shfl_xor(ss, m, 64);
    const float inv = 1.0f / fmaxf(sqrtf(ss), 1e-12f);
    float* dst = cbnt + (size_t)q * (DN * CN) + (size_t)(lane * 4) * CN + c;
    dst[0 * CN] = v.x * inv;
    dst[1 * CN] = v.y * inv;
    dst[2 * CN] = v.z * inv;
    dst[3 * CN] = v.w * inv;
}

// async global->LDS, 16B per lane (dest = wave-uniform base + lane*16)
__device__ __forceinline__ void acp16(float* lds_dst, const float* gsrc) {
    __builtin_amdgcn_global_load_lds(
        (const __attribute__((address_space(1))) unsigned int*)gsrc,
        (__attribute__((address_space(3))) unsigned int*)lds_dst, 16, 0, 0);
}

// 8 rows x 8 cods per thread, all accumulators individually named.
// Thread's cods within the 512-chunk: {cg*4+e} (aA) and {256+cg*4+e} (aB).
#define DECL_ROW(j) float4 aA##j = make_float4(0.f,0.f,0.f,0.f), \
                           aB##j = make_float4(0.f,0.f,0.f,0.f);

#define FMA_ROW(j, S) \
    aA##j.x = fmaf(S, b0.x, aA##j.x); aA##j.y = fmaf(S, b0.y, aA##j.y); \
    aA##j.z = fmaf(S, b0.z, aA##j.z); aA##j.w = fmaf(S, b0.w, aA##j.w); \
    aB##j.x = fmaf(S, b1.x, aB##j.x); aB##j.y = fmaf(S, b1.y, aB##j.y); \
    aB##j.z = fmaf(S, b1.z, aB##j.z); aB##j.w = fmaf(S, b1.w, aB##j.w);

#define KKSTEP(kk) { \
    const float4 a0 = *reinterpret_cast<const float4*>(&At[kt4 + (kk)][w8]); \
    const float4 a1 = *reinterpret_cast<const float4*>(&At[kt4 + (kk)][w8 + 4]); \
    const float4 b0 = *reinterpret_cast<const float4*>(&Btl[bb][kk][cg4]); \
    const float4 b1 = *reinterpret_cast<const float4*>(&Btl[bb][kk][256 + cg4]); \
    FMA_ROW(0, a0.x) FMA_ROW(1, a0.y) FMA_ROW(2, a0.z) FMA_ROW(3, a0.w) \
    FMA_ROW(4, a1.x) FMA_ROW(5, a1.y) FMA_ROW(6, a1.z) FMA_ROW(7, a1.w) }

// ascending cods within thread (cg*4+0..3 < 256+cg*4+0..3); strict > keeps first
#define FOLDMERGE(j) { \
    float bv = -INFINITY; int bi = 0; \
    const int cA = coff + cg4; \
    if (aA##j.x > bv) { bv = aA##j.x; bi = cA + 0; } \
    if (aA##j.y > bv) { bv = aA##j.y; bi = cA + 1; } \
    if (aA##j.z > bv) { bv = aA##j.z; bi = cA + 2; } \
    if (aA##j.w > bv) { bv = aA##j.w; bi = cA + 3; } \
    if (aB##j.x > bv) { bv = aB##j.x; bi = cA + 256; } \
    if (aB##j.y > bv) { bv = aB##j.y; bi = cA + 257; } \
    if (aB##j.z > bv) { bv = aB##j.z; bi = cA + 258; } \
    if (aB##j.w > bv) { bv = aB##j.w; bi = cA + 259; } \
    _Pragma("unroll") \
    for (int m = 1; m < 64; m <<= 1) { \
        const float ov = __shfl_xor(bv, m, 64); \
        const int   oi = __shfl_xor(bi, m, 64); \
        if (ov > bv || (ov == bv && oi < bi)) { bv = ov; bi = oi; } } \
    if (bv > rv##j) { rv##j = bv; ri##j = bi; } }

// stage one 4k x 512c B-tile (8 KiB): ONE acp16 per thread, linear LDS dest
#define STAGE(nb, tile) { \
    const float* s_ = cbtq + (size_t)(((tile) * 4 + (t >> 7)) * 1024) + coff + ((t & 127) << 2); \
    acp16(Bflat + (nb) * 2048 + (t << 2), s_); }

// ---------------------------------------------------------------------------
// Kernel 2: persistent RVQ, 512-thread WG owns 64 rows through all 8 stages.
// Residual in LDS At[k][row]; B double-buffered 4k x 512c tiles.
// amdgpu_waves_per_eu(4,4): allocator targets exactly 4 waves/EU (16 waves/CU,
// the LDS-imposed max) -> VGPR budget 128, no spill (round-5 lesson: the
// compiler otherwise aims for 8/EU, allocates 64 VGPRs, spills the acc tile).
// fmaf chain per (row,cod) is k=0..255 sequential — bit-identical to rounds 2/4/5.
// ---------------------------------------------------------------------------
__global__ __attribute__((amdgpu_flat_work_group_size(512, 512), amdgpu_waves_per_eu(4, 4)))
void rvq_main(const float* __restrict__ in,
              const float* __restrict__ cb,
              const float* __restrict__ cbnt,
              float* __restrict__ out) {
    __shared__ float At[DN][RPW];       // 64 KiB residual, transposed [k][row]
    __shared__ float Btl[2][4][512];    // 16 KiB: dbuf of 4k x 512c tiles
    float* Bflat = &Btl[0][0][0];
    int*   sIdx  = reinterpret_cast<int*>(Bflat);        // alias (64 ints, buf0)
    float* red   = Bflat + 64;                           // alias (8 floats)

    const int t    = threadIdx.x;
    const int r    = t & 63;            // row for elementwise phases
    const int w    = t >> 6;            // wave id 0..7 == GEMM row-group
    const int w8   = w << 3;
    const int cg4  = (t & 63) << 2;     // cod-group base within 512-chunk
    const int base = blockIdx.x * RPW;

    // residual := inputs; wave w handles k in [w*32, w*32+32) for all its lanes' rows
#pragma unroll
    for (int i = 0; i < 8; ++i) {
        const int k0 = (w << 5) + (i << 2);
        const float4 v = *reinterpret_cast<const float4*>(in + (size_t)(base + r) * DN + k0);
        At[k0 + 0][r] = v.x;
        At[k0 + 1][r] = v.y;
        At[k0 + 2][r] = v.z;
        At[k0 + 3][r] = v.w;
    }

    float lossAcc = 0.0f;

    for (int q = 0; q < QN; ++q) {
        const float* cbq  = cb   + (size_t)q * (CN * DN);
        const float* cbtq = cbnt + (size_t)q * (DN * CN);
        float rv0 = -INFINITY, rv1 = -INFINITY, rv2 = -INFINITY, rv3 = -INFINITY,
              rv4 = -INFINITY, rv5 = -INFINITY, rv6 = -INFINITY, rv7 = -INFINITY;
        int ri0 = 0, ri1 = 0, ri2 = 0, ri3 = 0, ri4 = 0, ri5 = 0, ri6 = 0, ri7 = 0;

        __syncthreads();                                 // At ready (init / prev update)

        for (int chunk = 0; chunk < 2; ++chunk) {        // 2 x 512 cods
            const int coff = chunk << 9;
            DECL_ROW(0) DECL_ROW(1) DECL_ROW(2) DECL_ROW(3)
            DECL_ROW(4) DECL_ROW(5) DECL_ROW(6) DECL_ROW(7)

            STAGE(0, 0)                                  // prologue: tile 0 -> buf 0

            for (int tt = 0; tt < 64; ++tt) {            // 64 tiles x 4 k
                __syncthreads();                          // vmcnt drained: buf[tt&1] ready
                const int bb = tt & 1;
                if (tt < 63) STAGE(bb ^ 1, tt + 1)        // next tile; hides under FMAs
                const int kt4 = tt * 4;
                KKSTEP(0) KKSTEP(1) KKSTEP(2) KKSTEP(3)
            }

            FOLDMERGE(0) FOLDMERGE(1) FOLDMERGE(2) FOLDMERGE(3)
            FOLDMERGE(4) FOLDMERGE(5) FOLDMERGE(6) FOLDMERGE(7)
        }

        __syncthreads();                 // everyone done with Btl before alias write
        if ((t & 63) == 0) {
            sIdx[w8 + 0] = ri0; sIdx[w8 + 1] = ri1;
            sIdx[w8 + 2] = ri2; sIdx[w8 + 3] = ri3;
            sIdx[w8 + 4] = ri4; sIdx[w8 + 5] = ri5;
            sIdx[w8 + 6] = ri6; sIdx[w8 + 7] = ri7;
        }
        __syncthreads();
        if (t < 64) out[(size_t)IDX_OFF + (size_t)q * NROWS + base + t] = (float)sIdx[t];

        // residual update + loss: wave w handles k in [w*32, w*32+32), all 64 rows
        {
            const int gi = sIdx[r];
            const float* qrow = cbq + (size_t)gi * DN + (w << 5);
#pragma unroll
            for (int i = 0; i < 8; ++i) {
                const float4 qv = *reinterpret_cast<const float4*>(qrow + (i << 2));
                const int k0 = (w << 5) + (i << 2);
                const float v0 = At[k0 + 0][r] - qv.x;
                const float v1 = At[k0 + 1][r] - qv.y;
                const float v2 = At[k0 + 2][r] - qv.z;
                const float v3 = At[k0 + 3][r] - qv.w;
                At[k0 + 0][r] = v0;
                At[k0 + 1][r] = v1;
                At[k0 + 2][r] = v2;
                At[k0 + 3][r] = v3;
                lossAcc += v0 * v0 + v1 * v1 + v2 * v2 + v3 * v3;
            }
        }
        // next iteration's leading __syncthreads covers At update + sIdx reuse
    }

    __syncthreads();

    // quantized_sum = inputs - residual_final
#pragma unroll
    for (int i = 0; i < 8; ++i) {
        const int k0 = (w << 5) + (i << 2);
        const float4 v = *reinterpret_cast<const float4*>(in + (size_t)(base + r) * DN + k0);
        float4 o;
        o.x = v.x - At[k0 + 0][r];
        o.y = v.y - At[k0 + 1][r];
        o.z = v.z - At[k0 + 2][r];
        o.w = v.w - At[k0 + 3][r];
        *reinterpret_cast<float4*>(out + (size_t)(base + r) * DN + k0) = o;
    }

    // loss: wave butterfly + cross-wave via LDS + one atomic per WG
#pragma unroll
    for (int m = 1; m < 64; m <<= 1) lossAcc += __shfl_xor(lossAcc, m, 64);
    if (r == 0) red[w] = lossAcc;
    __syncthreads();
    if (t == 0) {
        const float tot = red[0] + red[1] + red[2] + red[3]
                        + red[4] + red[5] + red[6] + red[7];
        atomicAdd(out + LOSS_OFF, tot * (1.25f / (8.0f * 8388608.0f)));
    }
}

extern "C" void kernel_launch(void* const* d_in, const int* in_sizes, int n_in,
                              void* d_out, int out_size, void* d_ws, size_t ws_size,
                              hipStream_t stream) {
    (void)in_sizes; (void)n_in; (void)out_size; (void)ws_size;
    const float* in   = (const float*)d_in[0];
    const float* cb   = (const float*)d_in[1];
    float* out        = (float*)d_out;
    float* cbnt       = (float*)d_ws;   // 8 MiB scratch: normalized+transposed codebooks

    rvq_normalize_cb<<<dim3(2048), dim3(256), 0, stream>>>(cb, cbnt, out);
    rvq_main<<<dim3(512), dim3(512), 0, stream>>>(in, cb, cbnt, out);
}